// Round 11
// baseline (504.269 us; speedup 1.0000x reference)
//
#include <hip/hip_runtime.h>
#include <hip/hip_bf16.h>
#include <stdint.h>

#define B_    16
#define NPTS_ 20000
#define H_    128
#define O_    4
#define L_    6
#define PDIM_ 8
#define K_    3

#define PTS_PER_WAVE 32
#define NTILES (NPTS_ / PTS_PER_WAVE)          // 625 (exact)
#define NBLOCKS (B_ * NTILES / 4)              // 2500 blocks x 4 waves

typedef __attribute__((ext_vector_type(8))) short short8;
typedef __attribute__((ext_vector_type(4))) float f32x4;
typedef __attribute__((ext_vector_type(2))) uint32_t u32x2;
typedef __attribute__((ext_vector_type(4))) uint32_t u32x4;

// XOR-swizzled slot for the per-wave pk scratch (verified conflict-free in R10)
#define XSL(lam) ((uint32_t)(((lam)*16) ^ (((((lam)>>3)&3))<<4)))

__device__ __forceinline__ uint32_t cvt_pk_bf16(float a, float b) {
    uint32_t d;
    asm("v_cvt_pk_bf16_f32 %0, %1, %2" : "=v"(d) : "v"(a), "v"(b));
    return d;
}
__device__ __forceinline__ float bf2f(uint16_t h) {
    return __uint_as_float(((uint32_t)h) << 16);
}
__device__ __forceinline__ uint16_t f2bf(float x) {
    uint32_t u = __float_as_uint(x);
    uint32_t r = u + 0x7FFFu + ((u >> 16) & 1u);
    return (uint16_t)(r >> 16);
}
__device__ __forceinline__ short8 mk8(uint32_t a, uint32_t b, uint32_t c, uint32_t d) {
    u32x4 t = (u32x4){a, b, c, d};
    return __builtin_bit_cast(short8, t);
}
__device__ __forceinline__ float bperm_f(int byteaddr, float v) {
    return __int_as_float(__builtin_amdgcn_ds_bpermute(byteaddr, __float_as_int(v)));
}

// x = S*tanh(z) + (a0*S)sin z + (2a1*S)sin z cos z + (a2*S)(3 sin z - 4 sin^3 z)
__device__ __forceinline__ float rowdy_cf(float z, float S, float mS,
                                          float A0, float A1, float A2) {
    float e, s1, c1;
    float zl = z * 2.8853900817779268f;       // 2*log2(e)
    asm("v_exp_f32 %0, %1" : "=v"(e) : "v"(zl));
    float r = __builtin_amdgcn_rcpf(e + 1.f);
    float acc = fmaf(mS, r, S);               // S*tanh(z)
    float zs = z * 0.15915494309189535f;      // 1/(2*pi)
    asm("v_sin_f32 %0, %1" : "=v"(s1) : "v"(zs));
    asm("v_cos_f32 %0, %1" : "=v"(c1) : "v"(zs));
    acc = fmaf(A0, s1, acc);
    acc = fmaf(A1, s1 * c1, acc);
    float t = s1 * s1;
    acc = fmaf(A2 * s1, fmaf(t, -4.f, 3.f), acc);
    return acc;
}

__device__ __forceinline__ void act_pack4_cf(const f32x4& v,
    const float4& S4, const float4& mS4, const float4& A0,
    const float4& A1, const float4& A2, u32x2& hi, u32x2& lo) {
    float x0 = rowdy_cf(v[0], S4.x, mS4.x, A0.x, A1.x, A2.x);
    float x1 = rowdy_cf(v[1], S4.y, mS4.y, A0.y, A1.y, A2.y);
    float x2 = rowdy_cf(v[2], S4.z, mS4.z, A0.z, A1.z, A2.z);
    float x3 = rowdy_cf(v[3], S4.w, mS4.w, A0.w, A1.w, A2.w);
    uint32_t d0 = cvt_pk_bf16(x0, x1);
    uint32_t d1 = cvt_pk_bf16(x2, x3);
    float r0 = x0 - __uint_as_float(d0 << 16);
    float r1 = x1 - __uint_as_float(d0 & 0xFFFF0000u);
    float r2 = x2 - __uint_as_float(d1 << 16);
    float r3 = x3 - __uint_as_float(d1 & 0xFFFF0000u);
    hi = (u32x2){d0, d1};
    lo = (u32x2){cvt_pk_bf16(r0, r1), cvt_pk_bf16(r2, r3)};
}

// ---------- fused prep (blocks 0..39) + branch tower (blocks 40..55) ----------
// Wf (ushort idx): ((layer*8+JF)*4+ks)*512 + ln*8
// element: j = JF*16 + (ln&15), k = ks*32 + (ln>>4)*8 + e
__global__ void prep_branch(
    const float* __restrict__ tWr,
    const float* __restrict__ params,
    const float* __restrict__ bW0, const float* __restrict__ bWr,
    const float* __restrict__ bb,  const float* __restrict__ bWout,
    const float* __restrict__ bbout,
    const float* __restrict__ fW,  const float* __restrict__ fb,
    const float* __restrict__ ra,
    uint16_t* __restrict__ WfH, uint16_t* __restrict__ WfL,
    float* __restrict__ CF, float* __restrict__ M, float* __restrict__ c0)
{
    const int blk = blockIdx.x;
    if (blk < 40) {
        const int layer = blk >> 3;
        const int JF    = blk & 7;
        const int t     = threadIdx.x;         // 256 = (ks, lane)
        const int ks    = t >> 6;
        const int ln    = t & 63;
        const int j     = JF * 16 + (ln & 15);
        const int kbase = ks * 32 + (ln >> 4) * 8;
        uint16_t hi[8], lo[8];
        #pragma unroll
        for (int e = 0; e < 8; ++e) {
            float w = tWr[((size_t)layer * H_ + kbase + e) * H_ + j];
            uint16_t h = f2bf(w);
            hi[e] = h;
            lo[e] = f2bf(w - bf2f(h));
        }
        size_t dst = ((size_t)((layer * 8 + JF) * 4 + ks) * 64 + ln) * 8;
        #pragma unroll
        for (int e = 0; e < 8; ++e) { WfH[dst + e] = hi[e]; WfL[dst + e] = lo[e]; }
        return;
    }

    const int b = blk - 40;
    const int j = threadIdx.x & 127;
    __shared__ float h[H_];
    __shared__ float zl[O_][H_];

    float z = bb[j];
    #pragma unroll
    for (int k = 0; k < PDIM_; ++k)
        z = fmaf(params[b * PDIM_ + k], bW0[k * H_ + j], z);
    float hv = tanhf(z);
    float srun = hv;
    h[j] = hv;
    {
        float* cf = CF + (size_t)(0 * B_ + b) * 4 * H_;
        cf[0 * H_ + j] = srun;
        cf[1 * H_ + j] = ra[(0 * K_ + 0) * H_ + j] * srun;
        cf[2 * H_ + j] = 2.f * ra[(0 * K_ + 1) * H_ + j] * srun;
        cf[3 * H_ + j] = ra[(0 * K_ + 2) * H_ + j] * srun;
    }

    for (int i = 1; i < L_; ++i) {
        __syncthreads();
        const float* W = bWr + (size_t)(i - 1) * H_ * H_;
        float zz = bb[i * H_ + j];
        for (int k = 0; k < H_; ++k)
            zz = fmaf(h[k], W[k * H_ + j], zz);
        __syncthreads();
        hv = tanhf(zz);
        h[j] = hv;
        srun += hv;
        float* cf = CF + (size_t)(i * B_ + b) * 4 * H_;
        cf[0 * H_ + j] = srun;
        cf[1 * H_ + j] = ra[(i * K_ + 0) * H_ + j] * srun;
        cf[2 * H_ + j] = 2.f * ra[(i * K_ + 1) * H_ + j] * srun;
        cf[3 * H_ + j] = ra[(i * K_ + 2) * H_ + j] * srun;
    }
    __syncthreads();

    #pragma unroll
    for (int o = 0; o < O_; ++o) {
        float acc = bbout[o * H_ + j];
        for (int k = 0; k < H_; ++k)
            acc = fmaf(h[k], bWout[(size_t)k * (H_ * O_) + o * H_ + j], acc);
        zl[o][j] = acc;
    }
    __syncthreads();

    float m[O_] = {0.f, 0.f, 0.f, 0.f};
    for (int hh = 0; hh < H_; ++hh) {
        float w = fW[j * H_ + hh];
        #pragma unroll
        for (int o = 0; o < O_; ++o)
            m[o] = fmaf(w, zl[o][hh], m[o]);
    }
    #pragma unroll
    for (int o = 0; o < O_; ++o)
        M[((size_t)b * H_ + j) * O_ + o] = m[o];

    if (j < O_) {
        float acc = 0.f;
        for (int hh = 0; hh < H_; ++hh)
            acc = fmaf(fb[hh], zl[j][hh], acc);
        c0[b * O_ + j] = acc;
    }
}

// ---------- trunk: 32 pts/wave, pf0 frags register-resident, barrier-free ----------
// 8 KB scratch/wave time-shared between the two 16-pt halves (pf0/pf1) via
// in-order per-wave DS (R10-verified). A-frags shared by both halves ->
// L2 W-traffic halved; launch_bounds(256,3) leaves ~30 VGPR of scheduling
// slack so the compiler can hoist A-loads over MFMAs (R10's VGPR=52 showed
// it had no room and serialized on L2 latency).
__global__ __launch_bounds__(256, 3) void trunk_mfma(
    const float* __restrict__ coords, const float* __restrict__ sdf,
    const float* __restrict__ tW0,    const float* __restrict__ tb,
    const float* __restrict__ CF,     const float* __restrict__ M,
    const float* __restrict__ c0,
    const uint16_t* __restrict__ WfH, const uint16_t* __restrict__ WfL,
    float* __restrict__ out)
{
    __shared__ __align__(16) uint8_t XPK[4][8192];   // 32 KiB/block

    const int t   = threadIdx.x;
    const int wv  = t >> 6;
    const int l   = t & 63;
    const int gid = blockIdx.x * 4 + wv;
    const int b    = gid / NTILES;
    const int tile = gid % NTILES;
    const int p0   = tile * PTS_PER_WAVE;
    const int m    = l >> 4;
    const int p15  = l & 15;
    const int j4b  = m * 4;

    uint8_t* lb = &XPK[wv][0];
    uint8_t* pW = lb + XSL(l);
    const int lamA = ((l & 16) << 1) | p15;
    uint8_t* pA = lb + (uint32_t)((m >> 1) * 1024) + XSL(lamA);
    uint8_t* pB = lb + (uint32_t)((m >> 1) * 1024) + XSL(lamA + 16);

    u32x4 RA0[4], RB0[4];      // pf0 B-frags, register-resident

    // ---- layer 0: both 16-pt halves through the shared scratch ----
    {
        const float* cf0 = CF + (size_t)b * 4 * H_;
        #pragma unroll 1
        for (int pf = 0; pf < 2; ++pf) {
            const size_t gp = (size_t)b * NPTS_ + p0 + pf * 16 + p15;
            float in0 = coords[gp * 3 + 0], in1 = coords[gp * 3 + 1];
            float in2 = coords[gp * 3 + 2], in3 = sdf[gp];
            #pragma unroll
            for (int JF = 0; JF < 8; ++JF) {
                const int j4 = JF * 16 + j4b;
                float4 w0 = *(const float4*)(tW0 + 0 * H_ + j4);
                float4 w1 = *(const float4*)(tW0 + 1 * H_ + j4);
                float4 w2 = *(const float4*)(tW0 + 2 * H_ + j4);
                float4 w3 = *(const float4*)(tW0 + 3 * H_ + j4);
                float4 bv = *(const float4*)(tb + j4);
                f32x4 zv;
                zv[0] = fmaf(in3, w3.x, fmaf(in2, w2.x, fmaf(in1, w1.x, fmaf(in0, w0.x, bv.x))));
                zv[1] = fmaf(in3, w3.y, fmaf(in2, w2.y, fmaf(in1, w1.y, fmaf(in0, w0.y, bv.y))));
                zv[2] = fmaf(in3, w3.z, fmaf(in2, w2.z, fmaf(in1, w1.z, fmaf(in0, w0.z, bv.z))));
                zv[3] = fmaf(in3, w3.w, fmaf(in2, w2.w, fmaf(in1, w1.w, fmaf(in0, w0.w, bv.w))));
                float4 S4 = *(const float4*)(cf0 + 0 * H_ + j4);
                float4 A0 = *(const float4*)(cf0 + 1 * H_ + j4);
                float4 A1 = *(const float4*)(cf0 + 2 * H_ + j4);
                float4 A2 = *(const float4*)(cf0 + 3 * H_ + j4);
                float4 mS4 = make_float4(-2.f * S4.x, -2.f * S4.y, -2.f * S4.z, -2.f * S4.w);
                u32x2 hi, lo;
                act_pack4_cf(zv, S4, mS4, A0, A1, A2, hi, lo);
                *(u32x4*)(pW + JF * 1024) = (u32x4){hi[0], hi[1], lo[0], lo[1]};
            }
            if (pf == 0) {
                #pragma unroll
                for (int ks = 0; ks < 4; ++ks) {
                    RA0[ks] = *(const u32x4*)(pA + ks * 2048);
                    RB0[ks] = *(const u32x4*)(pB + ks * 2048);
                }
            }
        }
    }

    // ---- layers 1..5 ----
    const uint16_t* WH = WfH;
    const uint16_t* WL = WfL;
    #pragma unroll 1
    for (int layer = 1; layer <= 5; ++layer) {
        f32x4 acc0[8], acc1[8];
        #pragma unroll
        for (int JF = 0; JF < 8; ++JF) {
            float4 bv = *(const float4*)(tb + layer * H_ + JF * 16 + j4b);
            acc0[JF] = (f32x4){bv.x, bv.y, bv.z, bv.w};
            acc1[JF] = acc0[JF];
        }
        #pragma unroll
        for (int ks = 0; ks < 4; ++ks) {
            u32x4 RA1 = *(const u32x4*)(pA + ks * 2048);   // pf1 frag, transient
            u32x4 RB1 = *(const u32x4*)(pB + ks * 2048);
            short8 bH0 = mk8(RA0[ks].x, RA0[ks].y, RB0[ks].x, RB0[ks].y);
            short8 bL0 = mk8(RA0[ks].z, RA0[ks].w, RB0[ks].z, RB0[ks].w);
            short8 bH1 = mk8(RA1.x, RA1.y, RB1.x, RB1.y);
            short8 bL1 = mk8(RA1.z, RA1.w, RB1.z, RB1.w);
            #pragma unroll
            for (int JF = 0; JF < 8; ++JF) {
                const size_t off = (size_t)((JF * 4 + ks) * 512) + l * 8;
                short8 aH = *(const short8*)(WH + off);
                short8 aL = *(const short8*)(WL + off);
                acc0[JF] = __builtin_amdgcn_mfma_f32_16x16x32_bf16(aH, bH0, acc0[JF], 0, 0, 0);
                acc0[JF] = __builtin_amdgcn_mfma_f32_16x16x32_bf16(aH, bL0, acc0[JF], 0, 0, 0);
                acc0[JF] = __builtin_amdgcn_mfma_f32_16x16x32_bf16(aL, bH0, acc0[JF], 0, 0, 0);
                acc1[JF] = __builtin_amdgcn_mfma_f32_16x16x32_bf16(aH, bH1, acc1[JF], 0, 0, 0);
                acc1[JF] = __builtin_amdgcn_mfma_f32_16x16x32_bf16(aH, bL1, acc1[JF], 0, 0, 0);
                acc1[JF] = __builtin_amdgcn_mfma_f32_16x16x32_bf16(aL, bH1, acc1[JF], 0, 0, 0);
            }
        }

        // act both halves; pf0 -> scratch now, pf1 held in regs until pf0 re-read
        const float* cf = CF + (size_t)(layer * B_ + b) * 4 * H_;
        u32x4 xp1[8];
        #pragma unroll
        for (int JF = 0; JF < 8; ++JF) {
            const int j4 = JF * 16 + j4b;
            float4 S4 = *(const float4*)(cf + 0 * H_ + j4);
            float4 A0 = *(const float4*)(cf + 1 * H_ + j4);
            float4 A1 = *(const float4*)(cf + 2 * H_ + j4);
            float4 A2 = *(const float4*)(cf + 3 * H_ + j4);
            float4 mS4 = make_float4(-2.f * S4.x, -2.f * S4.y, -2.f * S4.z, -2.f * S4.w);
            u32x2 hi, lo;
            act_pack4_cf(acc0[JF], S4, mS4, A0, A1, A2, hi, lo);
            *(u32x4*)(pW + JF * 1024) = (u32x4){hi[0], hi[1], lo[0], lo[1]};
            act_pack4_cf(acc1[JF], S4, mS4, A0, A1, A2, hi, lo);
            xp1[JF] = (u32x4){hi[0], hi[1], lo[0], lo[1]};
        }
        #pragma unroll
        for (int ks = 0; ks < 4; ++ks) {
            RA0[ks] = *(const u32x4*)(pA + ks * 2048);
            RB0[ks] = *(const u32x4*)(pB + ks * 2048);
        }
        #pragma unroll
        for (int JF = 0; JF < 8; ++JF)
            *(u32x4*)(pW + JF * 1024) = xp1[JF];

        WH += 8 * 2048;
        WL += 8 * 2048;
    }

    // ---- final: out[p][o] = c0[o] + sum_k x[k][p] * M[k][o], both halves ----
    {
        const float* Mb = M + (size_t)b * H_ * O_;
        float4 cv = *(const float4*)(c0 + b * O_);
        const int a16 = (l ^ 16) << 2;
        const int a32 = (l ^ 32) << 2;
        #pragma unroll 1
        for (int pf = 0; pf < 2; ++pf) {
            f32x4 part = (f32x4){0.f, 0.f, 0.f, 0.f};
            #pragma unroll
            for (int ks = 0; ks < 4; ++ks) {
                u32x4 RA, RB;
                if (pf == 0) { RA = RA0[ks]; RB = RB0[ks]; }
                else {
                    RA = *(const u32x4*)(pA + ks * 2048);
                    RB = *(const u32x4*)(pB + ks * 2048);
                }
                const int kb = ks * 32 + m * 8;
                uint32_t hw[4] = {RA.x, RA.y, RB.x, RB.y};
                uint32_t lw[4] = {RA.z, RA.w, RB.z, RB.w};
                #pragma unroll
                for (int q = 0; q < 4; ++q) {
                    float xe = __uint_as_float(hw[q] << 16) + __uint_as_float(lw[q] << 16);
                    float xo = __uint_as_float(hw[q] & 0xFFFF0000u) + __uint_as_float(lw[q] & 0xFFFF0000u);
                    float4 Me = *(const float4*)(Mb + (size_t)(kb + 2 * q) * O_);
                    float4 Mo = *(const float4*)(Mb + (size_t)(kb + 2 * q + 1) * O_);
                    part[0] = fmaf(xe, Me.x, part[0]); part[0] = fmaf(xo, Mo.x, part[0]);
                    part[1] = fmaf(xe, Me.y, part[1]); part[1] = fmaf(xo, Mo.y, part[1]);
                    part[2] = fmaf(xe, Me.z, part[2]); part[2] = fmaf(xo, Mo.z, part[2]);
                    part[3] = fmaf(xe, Me.w, part[3]); part[3] = fmaf(xo, Mo.w, part[3]);
                }
            }
            #pragma unroll
            for (int i = 0; i < 4; ++i) {
                float v = part[i];
                v += bperm_f(a16, v);
                v += bperm_f(a32, v);
                part[i] = v;
            }
            if (l < 16) {
                float4 o4 = make_float4(part[0] + cv.x, part[1] + cv.y,
                                        part[2] + cv.z, part[3] + cv.w);
                *(float4*)(out + ((size_t)b * NPTS_ + p0 + pf * 16 + l) * O_) = o4;
            }
        }
    }
}

extern "C" void kernel_launch(void* const* d_in, const int* in_sizes, int n_in,
                              void* d_out, int out_size, void* d_ws, size_t ws_size,
                              hipStream_t stream) {
    const float* coords  = (const float*)d_in[0];
    const float* sdf     = (const float*)d_in[1];
    const float* params  = (const float*)d_in[2];
    const float* bW0     = (const float*)d_in[3];
    const float* bWr     = (const float*)d_in[4];
    const float* bb      = (const float*)d_in[5];
    const float* bWout   = (const float*)d_in[6];
    const float* bbout   = (const float*)d_in[7];
    const float* tW0     = (const float*)d_in[8];
    const float* tWr     = (const float*)d_in[9];
    const float* tb      = (const float*)d_in[10];
    const float* ra      = (const float*)d_in[11];
    const float* fW      = (const float*)d_in[12];
    const float* fb      = (const float*)d_in[13];
    float* out = (float*)d_out;

    float* CF = (float*)d_ws;                           // 6*16*4*128 floats
    float* M  = CF + (size_t)L_ * B_ * 4 * H_;          // 16*128*4
    float* c0 = M + (size_t)B_ * H_ * O_;               // 64
    uint16_t* WfH = (uint16_t*)(c0 + B_ * O_);          // 5*128*128 ushort
    uint16_t* WfL = WfH + (size_t)(L_ - 1) * H_ * H_;

    prep_branch<<<dim3(40 + B_), dim3(256), 0, stream>>>(
        tWr, params, bW0, bWr, bb, bWout, bbout, fW, fb, ra,
        WfH, WfL, CF, M, c0);
    trunk_mfma<<<dim3(NBLOCKS), dim3(256), 0, stream>>>(
        coords, sdf, tW0, tb, CF, M, c0, WfH, WfL, out);
}

// Round 12
// 429.084 us; speedup vs baseline: 1.1752x; 1.1752x over previous
//
#include <hip/hip_runtime.h>
#include <hip/hip_bf16.h>
#include <stdint.h>

#define B_    16
#define NPTS_ 20000
#define H_    128
#define O_    4
#define L_    6
#define PDIM_ 8
#define K_    3

#define PTS_PER_WAVE 32
#define NTILES (NPTS_ / PTS_PER_WAVE)          // 625 (exact)
#define NBLOCKS (B_ * NTILES)                  // 10000 blocks x 1 wave

typedef __attribute__((ext_vector_type(8))) short short8;
typedef __attribute__((ext_vector_type(4))) float f32x4;
typedef __attribute__((ext_vector_type(2))) uint32_t u32x2;
typedef __attribute__((ext_vector_type(4))) uint32_t u32x4;

// XOR-swizzled slot (verified conflict-free, R10: SQ_LDS_BANK_CONFLICT = 0)
#define XSL(lam) ((uint32_t)(((lam)*16) ^ (((((lam)>>3)&3))<<4)))

__device__ __forceinline__ uint32_t cvt_pk_bf16(float a, float b) {
    uint32_t d;
    asm("v_cvt_pk_bf16_f32 %0, %1, %2" : "=v"(d) : "v"(a), "v"(b));
    return d;
}
__device__ __forceinline__ float bf2f(uint16_t h) {
    return __uint_as_float(((uint32_t)h) << 16);
}
__device__ __forceinline__ uint16_t f2bf(float x) {
    uint32_t u = __float_as_uint(x);
    uint32_t r = u + 0x7FFFu + ((u >> 16) & 1u);
    return (uint16_t)(r >> 16);
}
__device__ __forceinline__ short8 mk8(uint32_t a, uint32_t b, uint32_t c, uint32_t d) {
    u32x4 t = (u32x4){a, b, c, d};
    return __builtin_bit_cast(short8, t);
}
__device__ __forceinline__ float bperm_f(int byteaddr, float v) {
    return __int_as_float(__builtin_amdgcn_ds_bpermute(byteaddr, __float_as_int(v)));
}

// x = S*tanh(z) + (a0*S)sin z + (2a1*S)sin z cos z + (a2*S)(3 sin z - 4 sin^3 z)
__device__ __forceinline__ float rowdy_cf(float z, float S, float mS,
                                          float A0, float A1, float A2) {
    float e, s1, c1;
    float zl = z * 2.8853900817779268f;       // 2*log2(e)
    asm("v_exp_f32 %0, %1" : "=v"(e) : "v"(zl));
    float r = __builtin_amdgcn_rcpf(e + 1.f);
    float acc = fmaf(mS, r, S);               // S*tanh(z)
    float zs = z * 0.15915494309189535f;      // 1/(2*pi)
    asm("v_sin_f32 %0, %1" : "=v"(s1) : "v"(zs));
    asm("v_cos_f32 %0, %1" : "=v"(c1) : "v"(zs));
    acc = fmaf(A0, s1, acc);
    acc = fmaf(A1, s1 * c1, acc);
    float t = s1 * s1;
    acc = fmaf(A2 * s1, fmaf(t, -4.f, 3.f), acc);
    return acc;
}

__device__ __forceinline__ void act_pack4_cf(const f32x4& v,
    const float4& S4, const float4& mS4, const float4& A0,
    const float4& A1, const float4& A2, u32x2& hi, u32x2& lo) {
    float x0 = rowdy_cf(v[0], S4.x, mS4.x, A0.x, A1.x, A2.x);
    float x1 = rowdy_cf(v[1], S4.y, mS4.y, A0.y, A1.y, A2.y);
    float x2 = rowdy_cf(v[2], S4.z, mS4.z, A0.z, A1.z, A2.z);
    float x3 = rowdy_cf(v[3], S4.w, mS4.w, A0.w, A1.w, A2.w);
    uint32_t d0 = cvt_pk_bf16(x0, x1);
    uint32_t d1 = cvt_pk_bf16(x2, x3);
    float r0 = x0 - __uint_as_float(d0 << 16);
    float r1 = x1 - __uint_as_float(d0 & 0xFFFF0000u);
    float r2 = x2 - __uint_as_float(d1 << 16);
    float r3 = x3 - __uint_as_float(d1 & 0xFFFF0000u);
    hi = (u32x2){d0, d1};
    lo = (u32x2){cvt_pk_bf16(r0, r1), cvt_pk_bf16(r2, r3)};
}

// ---------- fused prep (blocks 0..39) + branch tower (blocks 40..55) ----------
// Wf (ushort idx): ((layer*8+JF)*4+ks)*512 + ln*8
// element: j = JF*16 + (ln&15), k = ks*32 + (ln>>4)*8 + e
__global__ void prep_branch(
    const float* __restrict__ tWr,
    const float* __restrict__ params,
    const float* __restrict__ bW0, const float* __restrict__ bWr,
    const float* __restrict__ bb,  const float* __restrict__ bWout,
    const float* __restrict__ bbout,
    const float* __restrict__ fW,  const float* __restrict__ fb,
    const float* __restrict__ ra,
    uint16_t* __restrict__ WfH, uint16_t* __restrict__ WfL,
    float* __restrict__ CF, float* __restrict__ M, float* __restrict__ c0)
{
    const int blk = blockIdx.x;
    if (blk < 40) {
        const int layer = blk >> 3;
        const int JF    = blk & 7;
        const int t     = threadIdx.x;         // 256 = (ks, lane)
        const int ks    = t >> 6;
        const int ln    = t & 63;
        const int j     = JF * 16 + (ln & 15);
        const int kbase = ks * 32 + (ln >> 4) * 8;
        uint16_t hi[8], lo[8];
        #pragma unroll
        for (int e = 0; e < 8; ++e) {
            float w = tWr[((size_t)layer * H_ + kbase + e) * H_ + j];
            uint16_t h = f2bf(w);
            hi[e] = h;
            lo[e] = f2bf(w - bf2f(h));
        }
        size_t dst = ((size_t)((layer * 8 + JF) * 4 + ks) * 64 + ln) * 8;
        #pragma unroll
        for (int e = 0; e < 8; ++e) { WfH[dst + e] = hi[e]; WfL[dst + e] = lo[e]; }
        return;
    }

    const int b = blk - 40;
    const int j = threadIdx.x & 127;
    __shared__ float h[H_];
    __shared__ float zl[O_][H_];

    float z = bb[j];
    #pragma unroll
    for (int k = 0; k < PDIM_; ++k)
        z = fmaf(params[b * PDIM_ + k], bW0[k * H_ + j], z);
    float hv = tanhf(z);
    float srun = hv;
    h[j] = hv;
    {
        float* cf = CF + (size_t)(0 * B_ + b) * 4 * H_;
        cf[0 * H_ + j] = srun;
        cf[1 * H_ + j] = ra[(0 * K_ + 0) * H_ + j] * srun;
        cf[2 * H_ + j] = 2.f * ra[(0 * K_ + 1) * H_ + j] * srun;
        cf[3 * H_ + j] = ra[(0 * K_ + 2) * H_ + j] * srun;
    }

    for (int i = 1; i < L_; ++i) {
        __syncthreads();
        const float* W = bWr + (size_t)(i - 1) * H_ * H_;
        float zz = bb[i * H_ + j];
        for (int k = 0; k < H_; ++k)
            zz = fmaf(h[k], W[k * H_ + j], zz);
        __syncthreads();
        hv = tanhf(zz);
        h[j] = hv;
        srun += hv;
        float* cf = CF + (size_t)(i * B_ + b) * 4 * H_;
        cf[0 * H_ + j] = srun;
        cf[1 * H_ + j] = ra[(i * K_ + 0) * H_ + j] * srun;
        cf[2 * H_ + j] = 2.f * ra[(i * K_ + 1) * H_ + j] * srun;
        cf[3 * H_ + j] = ra[(i * K_ + 2) * H_ + j] * srun;
    }
    __syncthreads();

    #pragma unroll
    for (int o = 0; o < O_; ++o) {
        float acc = bbout[o * H_ + j];
        for (int k = 0; k < H_; ++k)
            acc = fmaf(h[k], bWout[(size_t)k * (H_ * O_) + o * H_ + j], acc);
        zl[o][j] = acc;
    }
    __syncthreads();

    float m[O_] = {0.f, 0.f, 0.f, 0.f};
    for (int hh = 0; hh < H_; ++hh) {
        float w = fW[j * H_ + hh];
        #pragma unroll
        for (int o = 0; o < O_; ++o)
            m[o] = fmaf(w, zl[o][hh], m[o]);
    }
    #pragma unroll
    for (int o = 0; o < O_; ++o)
        M[((size_t)b * H_ + j) * O_ + o] = m[o];

    if (j < O_) {
        float acc = 0.f;
        for (int hh = 0; hh < H_; ++hh)
            acc = fmaf(fb[hh], zl[j][hh], acc);
        c0[b * O_ + j] = acc;
    }
}

// ---------- trunk: 1 wave/block, 32 pts/wave, single in-place scratch ----------
// All layer-n ds_reads are issued (MFMA phase) before any layer-(n+1)
// ds_write is issued; per-wave DS ordering makes in-place overwrite safe.
// No barriers anywhere. A-frags serve 32 points (6 MFMAs / 32 B) -> W L2
// traffic halved vs R10. launch_bounds(64,3): VGPR cap ~170, peak live
// ~110 (64 acc + transients) -> no spill, ~60 regs of hoisting slack.
__global__ __launch_bounds__(64, 3) void trunk_mfma(
    const float* __restrict__ coords, const float* __restrict__ sdf,
    const float* __restrict__ tW0,    const float* __restrict__ tb,
    const float* __restrict__ CF,     const float* __restrict__ M,
    const float* __restrict__ c0,
    const uint16_t* __restrict__ WfH, const uint16_t* __restrict__ WfL,
    float* __restrict__ out)
{
    __shared__ __align__(16) uint8_t XPK[16384];   // 16 KiB: [2 pf][8 KiB]

    const int l   = threadIdx.x;
    const int gid = blockIdx.x;
    const int b    = gid / NTILES;
    const int tile = gid % NTILES;
    const int p0   = tile * PTS_PER_WAVE;
    const int m    = l >> 4;
    const int p15  = l & 15;
    const int j4b  = m * 4;

    uint8_t* lb = &XPK[0];
    uint8_t* pW0 = lb + XSL(l);
    uint8_t* pW1 = lb + 8192 + XSL(l);
    const int lamA = ((l & 16) << 1) | p15;
    const uint32_t roff = (uint32_t)((m >> 1) * 1024);
    uint8_t* pA0 = lb + roff + XSL(lamA);
    uint8_t* pB0 = lb + roff + XSL(lamA + 16);
    uint8_t* pA1 = pA0 + 8192;
    uint8_t* pB1 = pB0 + 8192;

    // ---- layer 0: both 16-pt groups; W/CF loads shared ----
    {
        const size_t gp0 = (size_t)b * NPTS_ + p0 + p15;
        float i00 = coords[gp0 * 3 + 0], i01 = coords[gp0 * 3 + 1];
        float i02 = coords[gp0 * 3 + 2], i03 = sdf[gp0];
        const size_t gp1 = gp0 + 16;
        float i10 = coords[gp1 * 3 + 0], i11 = coords[gp1 * 3 + 1];
        float i12 = coords[gp1 * 3 + 2], i13 = sdf[gp1];
        const float* cf0 = CF + (size_t)b * 4 * H_;
        #pragma unroll
        for (int JF = 0; JF < 8; ++JF) {
            const int j4 = JF * 16 + j4b;
            float4 w0 = *(const float4*)(tW0 + 0 * H_ + j4);
            float4 w1 = *(const float4*)(tW0 + 1 * H_ + j4);
            float4 w2 = *(const float4*)(tW0 + 2 * H_ + j4);
            float4 w3 = *(const float4*)(tW0 + 3 * H_ + j4);
            float4 bv = *(const float4*)(tb + j4);
            float4 S4 = *(const float4*)(cf0 + 0 * H_ + j4);
            float4 A0 = *(const float4*)(cf0 + 1 * H_ + j4);
            float4 A1 = *(const float4*)(cf0 + 2 * H_ + j4);
            float4 A2 = *(const float4*)(cf0 + 3 * H_ + j4);
            float4 mS4 = make_float4(-2.f * S4.x, -2.f * S4.y, -2.f * S4.z, -2.f * S4.w);
            f32x4 zv;
            u32x2 hi, lo;
            zv[0] = fmaf(i03, w3.x, fmaf(i02, w2.x, fmaf(i01, w1.x, fmaf(i00, w0.x, bv.x))));
            zv[1] = fmaf(i03, w3.y, fmaf(i02, w2.y, fmaf(i01, w1.y, fmaf(i00, w0.y, bv.y))));
            zv[2] = fmaf(i03, w3.z, fmaf(i02, w2.z, fmaf(i01, w1.z, fmaf(i00, w0.z, bv.z))));
            zv[3] = fmaf(i03, w3.w, fmaf(i02, w2.w, fmaf(i01, w1.w, fmaf(i00, w0.w, bv.w))));
            act_pack4_cf(zv, S4, mS4, A0, A1, A2, hi, lo);
            *(u32x4*)(pW0 + JF * 1024) = (u32x4){hi[0], hi[1], lo[0], lo[1]};
            zv[0] = fmaf(i13, w3.x, fmaf(i12, w2.x, fmaf(i11, w1.x, fmaf(i10, w0.x, bv.x))));
            zv[1] = fmaf(i13, w3.y, fmaf(i12, w2.y, fmaf(i11, w1.y, fmaf(i10, w0.y, bv.y))));
            zv[2] = fmaf(i13, w3.z, fmaf(i12, w2.z, fmaf(i11, w1.z, fmaf(i10, w0.z, bv.z))));
            zv[3] = fmaf(i13, w3.w, fmaf(i12, w2.w, fmaf(i11, w1.w, fmaf(i10, w0.w, bv.w))));
            act_pack4_cf(zv, S4, mS4, A0, A1, A2, hi, lo);
            *(u32x4*)(pW1 + JF * 1024) = (u32x4){hi[0], hi[1], lo[0], lo[1]};
        }
    }

    // ---- layers 1..5 ----
    const uint16_t* WH = WfH;
    const uint16_t* WL = WfL;
    #pragma unroll 1
    for (int layer = 1; layer <= 5; ++layer) {
        f32x4 acc0[8], acc1[8];
        #pragma unroll
        for (int JF = 0; JF < 8; ++JF) {
            float4 bv = *(const float4*)(tb + layer * H_ + JF * 16 + j4b);
            acc0[JF] = (f32x4){bv.x, bv.y, bv.z, bv.w};
            acc1[JF] = acc0[JF];
        }
        #pragma unroll
        for (int ks = 0; ks < 4; ++ks) {
            u32x4 RA0 = *(const u32x4*)(pA0 + ks * 2048);
            u32x4 RB0 = *(const u32x4*)(pB0 + ks * 2048);
            u32x4 RA1 = *(const u32x4*)(pA1 + ks * 2048);
            u32x4 RB1 = *(const u32x4*)(pB1 + ks * 2048);
            short8 bH0 = mk8(RA0.x, RA0.y, RB0.x, RB0.y);
            short8 bL0 = mk8(RA0.z, RA0.w, RB0.z, RB0.w);
            short8 bH1 = mk8(RA1.x, RA1.y, RB1.x, RB1.y);
            short8 bL1 = mk8(RA1.z, RA1.w, RB1.z, RB1.w);
            #pragma unroll
            for (int JF = 0; JF < 8; ++JF) {
                const size_t off = (size_t)((JF * 4 + ks) * 512) + l * 8;
                short8 aH = *(const short8*)(WH + off);
                short8 aL = *(const short8*)(WL + off);
                acc0[JF] = __builtin_amdgcn_mfma_f32_16x16x32_bf16(aH, bH0, acc0[JF], 0, 0, 0);
                acc0[JF] = __builtin_amdgcn_mfma_f32_16x16x32_bf16(aH, bL0, acc0[JF], 0, 0, 0);
                acc0[JF] = __builtin_amdgcn_mfma_f32_16x16x32_bf16(aL, bH0, acc0[JF], 0, 0, 0);
                acc1[JF] = __builtin_amdgcn_mfma_f32_16x16x32_bf16(aH, bH1, acc1[JF], 0, 0, 0);
                acc1[JF] = __builtin_amdgcn_mfma_f32_16x16x32_bf16(aH, bL1, acc1[JF], 0, 0, 0);
                acc1[JF] = __builtin_amdgcn_mfma_f32_16x16x32_bf16(aL, bH1, acc1[JF], 0, 0, 0);
            }
        }
        // act + in-place overwrite (all reads above already issued)
        const float* cf = CF + (size_t)(layer * B_ + b) * 4 * H_;
        #pragma unroll
        for (int JF = 0; JF < 8; ++JF) {
            const int j4 = JF * 16 + j4b;
            float4 S4 = *(const float4*)(cf + 0 * H_ + j4);
            float4 A0 = *(const float4*)(cf + 1 * H_ + j4);
            float4 A1 = *(const float4*)(cf + 2 * H_ + j4);
            float4 A2 = *(const float4*)(cf + 3 * H_ + j4);
            float4 mS4 = make_float4(-2.f * S4.x, -2.f * S4.y, -2.f * S4.z, -2.f * S4.w);
            u32x2 hi, lo;
            act_pack4_cf(acc0[JF], S4, mS4, A0, A1, A2, hi, lo);
            *(u32x4*)(pW0 + JF * 1024) = (u32x4){hi[0], hi[1], lo[0], lo[1]};
            act_pack4_cf(acc1[JF], S4, mS4, A0, A1, A2, hi, lo);
            *(u32x4*)(pW1 + JF * 1024) = (u32x4){hi[0], hi[1], lo[0], lo[1]};
        }
        WH += 8 * 2048;
        WL += 8 * 2048;
    }

    // ---- final: out[p][o] = c0[o] + sum_k x[k][p] * M[k][o], both groups ----
    {
        const float* Mb = M + (size_t)b * H_ * O_;
        float4 cv = *(const float4*)(c0 + b * O_);
        const int a16 = (l ^ 16) << 2;
        const int a32 = (l ^ 32) << 2;
        #pragma unroll 1
        for (int pf = 0; pf < 2; ++pf) {
            const uint8_t* pA = pf ? pA1 : pA0;
            const uint8_t* pB = pf ? pB1 : pB0;
            f32x4 part = (f32x4){0.f, 0.f, 0.f, 0.f};
            #pragma unroll
            for (int ks = 0; ks < 4; ++ks) {
                u32x4 RA = *(const u32x4*)(pA + ks * 2048);
                u32x4 RB = *(const u32x4*)(pB + ks * 2048);
                const int kb = ks * 32 + m * 8;
                uint32_t hw[4] = {RA.x, RA.y, RB.x, RB.y};
                uint32_t lw[4] = {RA.z, RA.w, RB.z, RB.w};
                #pragma unroll
                for (int q = 0; q < 4; ++q) {
                    float xe = __uint_as_float(hw[q] << 16) + __uint_as_float(lw[q] << 16);
                    float xo = __uint_as_float(hw[q] & 0xFFFF0000u) + __uint_as_float(lw[q] & 0xFFFF0000u);
                    float4 Me = *(const float4*)(Mb + (size_t)(kb + 2 * q) * O_);
                    float4 Mo = *(const float4*)(Mb + (size_t)(kb + 2 * q + 1) * O_);
                    part[0] = fmaf(xe, Me.x, part[0]); part[0] = fmaf(xo, Mo.x, part[0]);
                    part[1] = fmaf(xe, Me.y, part[1]); part[1] = fmaf(xo, Mo.y, part[1]);
                    part[2] = fmaf(xe, Me.z, part[2]); part[2] = fmaf(xo, Mo.z, part[2]);
                    part[3] = fmaf(xe, Me.w, part[3]); part[3] = fmaf(xo, Mo.w, part[3]);
                }
            }
            #pragma unroll
            for (int i = 0; i < 4; ++i) {
                float v = part[i];
                v += bperm_f(a16, v);
                v += bperm_f(a32, v);
                part[i] = v;
            }
            if (l < 16) {
                float4 o4 = make_float4(part[0] + cv.x, part[1] + cv.y,
                                        part[2] + cv.z, part[3] + cv.w);
                *(float4*)(out + ((size_t)b * NPTS_ + p0 + pf * 16 + l) * O_) = o4;
            }
        }
    }
}

extern "C" void kernel_launch(void* const* d_in, const int* in_sizes, int n_in,
                              void* d_out, int out_size, void* d_ws, size_t ws_size,
                              hipStream_t stream) {
    const float* coords  = (const float*)d_in[0];
    const float* sdf     = (const float*)d_in[1];
    const float* params  = (const float*)d_in[2];
    const float* bW0     = (const float*)d_in[3];
    const float* bWr     = (const float*)d_in[4];
    const float* bb      = (const float*)d_in[5];
    const float* bWout   = (const float*)d_in[6];
    const float* bbout   = (const float*)d_in[7];
    const float* tW0     = (const float*)d_in[8];
    const float* tWr     = (const float*)d_in[9];
    const float* tb      = (const float*)d_in[10];
    const float* ra      = (const float*)d_in[11];
    const float* fW      = (const float*)d_in[12];
    const float* fb      = (const float*)d_in[13];
    float* out = (float*)d_out;

    float* CF = (float*)d_ws;                           // 6*16*4*128 floats
    float* M  = CF + (size_t)L_ * B_ * 4 * H_;          // 16*128*4
    float* c0 = M + (size_t)B_ * H_ * O_;               // 64
    uint16_t* WfH = (uint16_t*)(c0 + B_ * O_);          // 5*128*128 ushort
    uint16_t* WfL = WfH + (size_t)(L_ - 1) * H_ * H_;

    prep_branch<<<dim3(40 + B_), dim3(256), 0, stream>>>(
        tWr, params, bW0, bWr, bb, bWout, bbout, fW, fb, ra,
        WfH, WfL, CF, M, c0);
    trunk_mfma<<<dim3(NBLOCKS), dim3(64), 0, stream>>>(
        coords, sdf, tW0, tb, CF, M, c0, WfH, WfL, out);
}